// Round 10
// baseline (3156.667 us; speedup 1.0000x reference)
//
#include <hip/hip_runtime.h>

// SolarRNN: B=256, T=4096, F=16, H=64. Two fused GRU layers + online-softmax
// attention + MLP tail. Block b = sequence b.
//
// R10 = R7's verified per-wave geometry (K-split-4, lane=(o=j>>2,s=j&3),
// col=16v+o, rotated hoff reads, qsum, <=48 v2f/wave -- the proven-allocatable
// footprint) with the block-wide barrier replaced by TWO DECOUPLED GROUPS:
//   L1-group (waves 0-3): self-contained GRU1 (x + own h1 ring). Runs AHEAD.
//     Publishes h1(t),o1(t) to 8-deep rings; per-step 4-flag group rendezvous.
//   L2-group (waves 4-7): in2 = o1@Wi2 + bi2 (direct -- Wp-fold deleted),
//     own h2 double-buffer, online softmax (1-step spl skew, R6-verified).
// Cross-group sync: monotone counters pg1[4]/pg2[4]. L2 waits pg1>=t+4 every
// 4 steps (L1 ahead -> normally non-blocking); L1 back-pressure pg2>=t-4
// every 4 steps (ring depth 8 > slack 7). Forward-only, bounded spins
// (s_sleep(1), 8192 iters): a protocol bug -> wrong numerics, never a hang.
// Each SIMD hosts one L1 + one L2 wave; group idle time feeds the co-wave.

#define B_ 256
#define T_ 4096
#define F_ 16
#define H_ 64
#define L2E 1.4426950408889634f
#define DEPTH 8

typedef float v2f __attribute__((ext_vector_type(2)));

__device__ __forceinline__ float sigm(float x) {
    float e = __builtin_amdgcn_exp2f(-L2E * x);
    return __builtin_amdgcn_rcpf(1.0f + e);
}
__device__ __forceinline__ float tanh_(float x) {
    float e = __builtin_amdgcn_exp2f(2.0f * L2E * x);
    return 1.0f - 2.0f * __builtin_amdgcn_rcpf(1.0f + e);
}
__device__ __forceinline__ v2f fma2(v2f a, v2f b, v2f c) {
    return __builtin_elementwise_fma(a, b, c);
}

#define DPPADD(x, ctrl) \
    ((x) + __builtin_bit_cast(float, __builtin_amdgcn_update_dpp( \
        0, __builtin_bit_cast(int, (x)), (ctrl), 0xF, 0xF, true)))

__device__ __forceinline__ float qsum(float x) {
    float t = DPPADD(x, 0xB1);   // quad_perm [1,0,3,2]
    return DPPADD(t, 0x4E);      // quad_perm [2,3,0,1]
}
__device__ __forceinline__ float wred(float x) {
    x = DPPADD(x, 0x111);
    x = DPPADD(x, 0x112);
    x = DPPADD(x, 0x114);
    x = DPPADD(x, 0x118);
    x = DPPADD(x, 0x142);
    x = DPPADD(x, 0x143);
    return x;                    // total in lane 63
}

#define LGKM0() asm volatile("s_waitcnt lgkmcnt(0)" ::: "memory")

// wait until all 4 counters >= tgt; bounded; clobber forces LDS re-reads.
__device__ __forceinline__ void grpwait(volatile const int* f, int tgt) {
    int g = 0;
    while ((f[0] < tgt) | (f[1] < tgt) | (f[2] < tgt) | (f[3] < tgt)) {
        __builtin_amdgcn_s_sleep(1);
        if (++g >= 8192) break;
    }
    asm volatile("" ::: "memory");
}

__launch_bounds__(512, 1)
__global__ void solar_rnn(const float* __restrict__ x,
                          const float* __restrict__ Wi1, const float* __restrict__ bi1,
                          const float* __restrict__ Whr1, const float* __restrict__ Whz1,
                          const float* __restrict__ Whn1, const float* __restrict__ bhn1,
                          const float* __restrict__ Wi2, const float* __restrict__ bi2,
                          const float* __restrict__ Whr2, const float* __restrict__ Whz2,
                          const float* __restrict__ Whn2, const float* __restrict__ bhn2,
                          const float* __restrict__ Wp, const float* __restrict__ bp,
                          const float* __restrict__ Wa,
                          const float* __restrict__ W1, const float* __restrict__ b1,
                          const float* __restrict__ W2, const float* __restrict__ b2,
                          const float* __restrict__ W3, const float* __restrict__ b3,
                          const float* __restrict__ W4, const float* __restrict__ b4,
                          float* __restrict__ out)
{
    const int b   = blockIdx.x;
    const int tid = threadIdx.x;
    const int w   = tid >> 6;        // wave 0..7
    const int j   = tid & 63;
    const bool l2r = (w >= 4);       // 0-3 = L1-group, 4-7 = L2-group
    const int v   = w & 3;
    const int o   = j >> 2;
    const int s   = j & 3;           // k-slice [16s,16s+16)
    const int col = 16 * v + o;

    __shared__ float h1r[DEPTH][H_];     // h1 ring (L1-internal)
    __shared__ float o1g[DEPTH][H_];     // o1 ring  L1 -> L2
    __shared__ float h2r[2][H_];         // h2 double-buffer (L2-internal)
    __shared__ float spl[2][4];          // score partials (L2, 1-step skew)
    __shared__ __align__(16) float xsh[2][256];  // x chunks (L1-group)
    __shared__ int pg1[4], pg2[4];
    __shared__ float sm_a[128];
    __shared__ float sm_b[128];
    volatile int* vp1 = pg1;
    volatile int* vp2 = pg2;

    int hoff[4];
    #pragma unroll
    for (int q = 0; q < 4; ++q) hoff[q] = 16 * s + 4 * ((q + s) & 3);

    // ---- per-role weights (R7 footprint: <=48 v2f + small) ----
    v2f hw0[8], hw1[8], hw2[8], hw3[8], hw4[8], hw5[8];
    v2f xw0[2], xw1[2], xw2[2], xw3[2];
    float c0, c1, c2, c3, c4;

    if (!l2r) {
        #pragma unroll
        for (int q = 0; q < 4; ++q) {
            const int rb = hoff[q];
            #pragma unroll
            for (int e = 0; e < 2; ++e) {
                const int r0 = rb + 2 * e, r1 = r0 + 1, m = 2 * q + e;
                hw0[m] = v2f{Whr1[r0 * H_ + col], Whr1[r1 * H_ + col]};
                hw1[m] = v2f{Whz1[r0 * H_ + col], Whz1[r1 * H_ + col]};
                hw2[m] = v2f{Whn1[r0 * H_ + col], Whn1[r1 * H_ + col]};
            }
        }
        #pragma unroll
        for (int m = 0; m < 2; ++m) {
            const int r0 = 4 * s + 2 * m, r1 = r0 + 1;
            xw0[m] = v2f{Wi1[r0 * 192 + col],       Wi1[r1 * 192 + col]};
            xw1[m] = v2f{Wi1[r0 * 192 + 64 + col],  Wi1[r1 * 192 + 64 + col]};
            xw2[m] = v2f{Wi1[r0 * 192 + 128 + col], Wi1[r1 * 192 + 128 + col]};
            xw3[m] = v2f{Wp[r0 * H_ + col],         Wp[r1 * H_ + col]};
        }
        c0 = bi1[col]; c1 = bi1[64 + col]; c2 = bi1[128 + col];
        c3 = bhn1[col]; c4 = bp[col];
    } else {
        #pragma unroll
        for (int q = 0; q < 4; ++q) {
            const int rb = hoff[q];
            #pragma unroll
            for (int e = 0; e < 2; ++e) {
                const int r0 = rb + 2 * e, r1 = r0 + 1, m = 2 * q + e;
                hw0[m] = v2f{Whr2[r0 * H_ + col], Whr2[r1 * H_ + col]};
                hw1[m] = v2f{Whz2[r0 * H_ + col], Whz2[r1 * H_ + col]};
                hw2[m] = v2f{Whn2[r0 * H_ + col], Whn2[r1 * H_ + col]};
                hw3[m] = v2f{Wi2[r0 * 192 + col],       Wi2[r1 * 192 + col]};
                hw4[m] = v2f{Wi2[r0 * 192 + 64 + col],  Wi2[r1 * 192 + 64 + col]};
                hw5[m] = v2f{Wi2[r0 * 192 + 128 + col], Wi2[r1 * 192 + 128 + col]};
            }
        }
        c0 = bi2[col]; c1 = bi2[64 + col]; c2 = bi2[128 + col];
        c3 = bhn2[col]; c4 = Wa[col];
        // ba: softmax shift-invariant, skipped.
    }

    // ---- init ----
    if (tid < 64) h1r[DEPTH - 1][j] = 0.f;     // h1(-1)
    if (tid < 64) { h2r[0][j] = 0.f; h2r[1][j] = 0.f; }
    if (tid < 4)  { pg1[tid] = 0; pg2[tid] = 0; }
    const float* xb = x + (size_t)b * T_ * F_;
    float4 xnext;
    if (w == 0) {
        ((float4*)&xsh[0][0])[j] = ((const float4*)xb)[j];
        xnext = ((const float4*)xb)[64 + j];
    }
    __syncthreads();

    const v2f zz = v2f{0.f, 0.f};
    float hS = 0.f;

    if (!l2r) {
        // ===================== L1-group (runs ahead) =====================
        #pragma unroll 1
        for (int t = 0; t < T_; ++t) {
            if ((t & 3) == 0 && t >= DEPTH)
                grpwait(vp2, t - 4);                 // ring back-pressure
            grpwait(vp1, t);                         // group rendezvous

            const float4 xt4 = ((const float4*)xsh[(t >> 4) & 1])[(t & 15) * 4 + s];
            const float* hr = h1r[(t + DEPTH - 1) & (DEPTH - 1)];   // h1(t-1)
            v2f hv[8];
            #pragma unroll
            for (int q = 0; q < 4; ++q) {
                const float4 a = *(const float4*)&hr[hoff[q]];
                hv[2 * q]     = v2f{a.x, a.y};
                hv[2 * q + 1] = v2f{a.z, a.w};
            }
            const v2f xt0 = v2f{xt4.x, xt4.y}, xt1 = v2f{xt4.z, xt4.w};
            v2f Ar = fma2(xw0[0], xt0, fma2(xw0[1], xt1, zz));
            v2f Az = fma2(xw1[0], xt0, fma2(xw1[1], xt1, zz));
            v2f An = fma2(xw2[0], xt0, fma2(xw2[1], xt1, zz));
            v2f Ax = fma2(xw3[0], xt0, fma2(xw3[1], xt1, zz));
            v2f Ah = zz;
            #pragma unroll
            for (int m = 0; m < 8; ++m) {
                Ar = fma2(hv[m], hw0[m], Ar);
                Az = fma2(hv[m], hw1[m], Az);
                Ah = fma2(hv[m], hw2[m], Ah);
            }
            const float g0 = qsum(Ar.x + Ar.y);
            const float g1 = qsum(Az.x + Az.y);
            const float g2 = qsum(An.x + An.y);
            const float g3 = qsum(Ah.x + Ah.y);
            const float g4 = qsum(Ax.x + Ax.y);
            const float r1 = sigm(g0 + c0);
            const float z1 = sigm(g1 + c1);
            const float n1 = tanh_((g2 + c2) + r1 * (g3 + c3));
            hS = n1 + z1 * (hS - n1);
            const float o1 = hS + 0.5f * (g4 + c4);
            if (s == 0) {
                h1r[t & (DEPTH - 1)][col] = hS;
                o1g[t & (DEPTH - 1)][col] = o1;
            }
            if ((t & 15) == 8 && w == 0) {
                const int c = (t >> 4) + 1;
                if (c < T_ / 16) {
                    ((float4*)&xsh[c & 1][0])[j] = xnext;
                    if (c + 1 < T_ / 16) xnext = ((const float4*)xb)[(c + 1) * 64 + j];
                }
            }
            LGKM0();
            if (j == 0) vp1[v] = t + 1;
        }
    } else {
        // ===================== L2-group (trails) =====================
        float o2a = 0.f;
        float am = -3.0e38f, al = 0.f, aa = 0.f;

        #pragma unroll 1
        for (int t = 0; t < T_; ++t) {
            if ((t & 3) == 0) {
                const int need = (t + 4 <= T_) ? t + 4 : T_;
                grpwait(vp1, need);                  // o1(t..t+3) available
            }
            grpwait(vp2, t);                         // group rendezvous

            const float* orow = o1g[t & (DEPTH - 1)];
            const float* hr   = h2r[(t + 1) & 1];    // h2(t-1)
            v2f ov[8], gv[8];
            #pragma unroll
            for (int q = 0; q < 4; ++q) {
                const float4 a = *(const float4*)&orow[hoff[q]];
                const float4 c = *(const float4*)&hr[hoff[q]];
                ov[2 * q]     = v2f{a.x, a.y};
                ov[2 * q + 1] = v2f{a.z, a.w};
                gv[2 * q]     = v2f{c.x, c.y};
                gv[2 * q + 1] = v2f{c.z, c.w};
            }
            const float o1own = orow[col];
            float gp = spl[(t + 1) & 1][s];          // ps(t-1) partials

            v2f Ar = zz, Az = zz, An = zz, Ah = zz;
            #pragma unroll
            for (int m = 0; m < 8; ++m) {
                Ar = fma2(ov[m], hw3[m], Ar);        // o1 @ Wi2 (r,z,n)
                Az = fma2(ov[m], hw4[m], Az);
                An = fma2(ov[m], hw5[m], An);
                Ar = fma2(gv[m], hw0[m], Ar);        // h2 @ Wh*2
                Az = fma2(gv[m], hw1[m], Az);
                Ah = fma2(gv[m], hw2[m], Ah);
            }
            const float g6 = qsum(Ar.x + Ar.y);
            const float g7 = qsum(Az.x + Az.y);
            const float g5 = qsum(An.x + An.y);
            const float g8 = qsum(Ah.x + Ah.y);
            gp = qsum(gp);

            // softmax apply for step t-1
            if (t >= 1) {
                const float p  = 0.25f * gp;
                const float mn = fmaxf(am, p);
                const float ca = __builtin_amdgcn_exp2f((am - mn) * L2E);
                const float ce = __builtin_amdgcn_exp2f((p  - mn) * L2E);
                al = fmaf(al, ca, ce);
                aa = fmaf(aa, ca, ce * o2a);
                am = mn;
            }

            const float r2 = sigm(g6 + c0);
            const float z2 = sigm(g7 + c1);
            const float n2 = tanh_((g5 + c2) + r2 * (g8 + c3));
            hS = n2 + z2 * (hS - n2);
            const float o2 = hS + 0.5f * o1own;
            float ps = wred(o2 * c4);
            if (j == 63) spl[t & 1][v] = ps;
            if (s == 0) h2r[t & 1][col] = hS;
            o2a = o2;
            LGKM0();
            if (j == 0) vp2[v] = t + 1;
        }
        // epilogue: softmax for step T-1
        grpwait(vp2, T_);
        float gq = qsum(spl[(T_ + 1) & 1][s]);
        {
            const float p  = 0.25f * gq;
            const float mn = fmaxf(am, p);
            const float ca = __builtin_amdgcn_exp2f((am - mn) * L2E);
            const float ce = __builtin_amdgcn_exp2f((p  - mn) * L2E);
            al = fmaf(al, ca, ce);
            aa = fmaf(aa, ca, ce * o2a);
        }
        if (s == 0) sm_a[col] = aa / al;             // attended vector
    }

    __syncthreads();

    // ---- MLP tail (once per block) ----
    float v1 = 0.f;
    if (tid < 128) {
        float a = b1[tid];
        for (int k = 0; k < 64; ++k) a = fmaf(sm_a[k], W1[k * 128 + tid], a);
        v1 = fmaxf(a, 0.f);
    }
    __syncthreads();
    if (tid < 128) sm_b[tid] = v1;
    __syncthreads();
    if (tid < 64) {
        float a = b2[tid];
        for (int k = 0; k < 128; ++k) a = fmaf(sm_b[k], W2[k * 64 + tid], a);
        sm_a[tid] = fmaxf(a, 0.f);
    }
    __syncthreads();
    if (tid < 32) {
        float a = b3[tid];
        for (int k = 0; k < 64; ++k) a = fmaf(sm_a[k], W3[k * 32 + tid], a);
        sm_b[tid] = fmaxf(a, 0.f);
    }
    __syncthreads();
    if (tid < 2) {
        float a = b4[tid];
        for (int k = 0; k < 32; ++k) a = fmaf(sm_b[k], W4[k * 2 + tid], a);
        out[b * 2 + tid] = a;
    }
}

extern "C" void kernel_launch(void* const* d_in, const int* in_sizes, int n_in,
                              void* d_out, int out_size, void* d_ws, size_t ws_size,
                              hipStream_t stream) {
    const float* x    = (const float*)d_in[0];
    const float* Wi1  = (const float*)d_in[1];
    const float* bi1  = (const float*)d_in[2];
    const float* Whr1 = (const float*)d_in[3];
    const float* Whz1 = (const float*)d_in[4];
    const float* Whn1 = (const float*)d_in[5];
    const float* bhn1 = (const float*)d_in[6];
    const float* Wi2  = (const float*)d_in[7];
    const float* bi2  = (const float*)d_in[8];
    const float* Whr2 = (const float*)d_in[9];
    const float* Whz2 = (const float*)d_in[10];
    const float* Whn2 = (const float*)d_in[11];
    const float* bhn2 = (const float*)d_in[12];
    const float* Wp   = (const float*)d_in[13];
    const float* bp   = (const float*)d_in[14];
    const float* Wa   = (const float*)d_in[15];
    // d_in[16] = ba: softmax shift-invariant, unused
    const float* W1   = (const float*)d_in[17];
    const float* b1   = (const float*)d_in[18];
    const float* W2   = (const float*)d_in[19];
    const float* b2   = (const float*)d_in[20];
    const float* W3   = (const float*)d_in[21];
    const float* b3   = (const float*)d_in[22];
    const float* W4   = (const float*)d_in[23];
    const float* b4   = (const float*)d_in[24];

    solar_rnn<<<dim3(B_), dim3(512), 0, stream>>>(
        x, Wi1, bi1, Whr1, Whz1, Whn1, bhn1,
        Wi2, bi2, Whr2, Whz2, Whn2, bhn2,
        Wp, bp, Wa, W1, b1, W2, b2, W3, b3, W4, b4,
        (float*)d_out);
}